// Round 13
// baseline (136.466 us; speedup 1.0000x reference)
//
#include <hip/hip_runtime.h>

#define S_LEN 2048
#define DM    1024
#define NHEAD 16
#define HDIM  64
#define NB    2
#define NROWS (NB * S_LEN)   // 4096
#define RCP_LN2 1.44269504f

using f32x4  = __attribute__((ext_vector_type(4))) float;
using f16x8  = __attribute__((ext_vector_type(8))) _Float16;

__device__ __forceinline__ ushort f2h(float f) {
  return __builtin_bit_cast(ushort, (_Float16)f);
}
__device__ __forceinline__ unsigned pkrtz(float a, float b) {
  return __builtin_bit_cast(unsigned, __builtin_amdgcn_cvt_pkrtz(a, b));
}
__device__ __forceinline__ float fexp2(float x) {     // raw v_exp_f32
  return __builtin_amdgcn_exp2f(x);
}
__device__ __forceinline__ f32x4 mfma16(f16x8 a, f16x8 b, f32x4 c) {
  return __builtin_amdgcn_mfma_f32_16x16x32_f16(a, b, c, 0, 0, 0);
}
__device__ __forceinline__ void async16(const ushort* g, ushort* l) {
  __builtin_amdgcn_global_load_lds(
      (const __attribute__((address_space(1))) unsigned*)g,
      (__attribute__((address_space(3))) unsigned*)l, 16, 0, 0);
}

// job type tables (KVBLK=64 units): 24 types, sorted by length desc.
// hf: 0=front half, 1=back half, 2=whole
__device__ const int g_qi_tab[24] = {15,15,7,14,14,13,13,6,12,12,11,11,
                                     5,10,10,9,9,4,8,8,3,2,1,0};
__device__ const int g_hf_tab[24] = {0,1,2,0,1,0,1,2,0,1,0,1,
                                     2,0,1,0,1,2,0,1,2,2,2,2};

// ---------------- fused fp32 -> fp16 for x, Wq, Wk, Wv, Wo ----------------
__global__ void tohalf5(const float* __restrict__ x,  const float* __restrict__ wq,
                        const float* __restrict__ wk, const float* __restrict__ wv,
                        const float* __restrict__ wo,
                        ushort* __restrict__ Xh, ushort* __restrict__ Wh,
                        ushort* __restrict__ Woh) {
  constexpr int X4 = (NROWS * DM) / 4;
  constexpr int W4 = (DM * DM) / 4;
  const size_t WN = (size_t)DM * DM;
  int i = blockIdx.x * 256 + threadIdx.x;
  const float4* src; ushort4* dst; int k;
  if (i < X4)               { src = (const float4*)x;  dst = (ushort4*)Xh;        k = i; }
  else if (i < X4 + W4)     { src = (const float4*)wq; dst = (ushort4*)Wh;        k = i - X4; }
  else if (i < X4 + 2*W4)   { src = (const float4*)wk; dst = (ushort4*)(Wh+WN);   k = i - X4 - W4; }
  else if (i < X4 + 3*W4)   { src = (const float4*)wv; dst = (ushort4*)(Wh+2*WN); k = i - X4 - 2*W4; }
  else                      { src = (const float4*)wo; dst = (ushort4*)Woh;       k = i - X4 - 3*W4; }
  float4 v = src[k];
  dst[k] = make_ushort4(f2h(v.x), f2h(v.y), f2h(v.z), f2h(v.w));
}

// ---------------- fp16 NT GEMM: C = A[M,K] * (B[N,K])^T ----------------
template<int EPI, int MFRAG, int NFRAG>
__global__ __launch_bounds__(256, 2)
void gemm_half(const ushort* __restrict__ A, const ushort* __restrict__ B,
               const float* __restrict__ biasQ, const float* __restrict__ biasK,
               const float* __restrict__ biasV,
               float* __restrict__ outF,
               ushort* __restrict__ Q, ushort* __restrict__ Kd,
               ushort* __restrict__ Vt, int Ncols)
{
  constexpr int KD = 1024;
  constexpr int BM = MFRAG * 32, BN = NFRAG * 32;
  constexpr int NCH = (BM + BN) / 8;
  constexpr int CPW = NCH / 4;
  __shared__ ushort sL[(BM + BN) * 64];
  const int t = threadIdx.x;
  const int w = t >> 6, l = t & 63;
  const int lr = l >> 4, lc = l & 15;
  const int wr = w >> 1, wc = w & 1;
  const int nwg = gridDim.x * gridDim.y;
  const int lin = blockIdx.y * gridDim.x + blockIdx.x;
  const int per8 = nwg >> 3;
  const int swz = (lin & 7) * per8 + (lin >> 3);
  const int i0 = (swz / gridDim.x) * BM, j0 = (swz % gridDim.x) * BN;

  const int srow = l >> 3;
  const int se   = ((l & 7) ^ srow) << 3;

  const ushort* sp[CPW];
#pragma unroll
  for (int ii = 0; ii < CPW; ++ii) {
    const int c = w * CPW + ii;
    sp[ii] = (c < BM / 8)
        ? A + (size_t)(i0 + c * 8 + srow) * KD + se
        : B + (size_t)(j0 + (c - BM / 8) * 8 + srow) * KD + se;
  }

  f32x4 acc[MFRAG][NFRAG] = {};

  for (int k0 = 0; k0 < KD; k0 += 64) {
#pragma unroll
    for (int ii = 0; ii < CPW; ++ii) {
      async16(sp[ii], &sL[(w * CPW + ii) * 512]);
      sp[ii] += 64;
    }
    asm volatile("s_waitcnt vmcnt(0)" ::: "memory");
    __syncthreads();
#pragma unroll
    for (int kk = 0; kk < 2; ++kk) {
      const int cb = (kk * 64 + lr * 16) ^ ((lc & 7) << 4);
      f16x8 a[MFRAG], b[NFRAG];
#pragma unroll
      for (int m = 0; m < MFRAG; ++m)
        a[m] = *(const f16x8*)&sL[(wr * MFRAG * 16 + m * 16 + lc) * 64 + (cb >> 1)];
#pragma unroll
      for (int n = 0; n < NFRAG; ++n)
        b[n] = *(const f16x8*)&sL[BM * 64 + (wc * NFRAG * 16 + n * 16 + lc) * 64 + (cb >> 1)];
      __builtin_amdgcn_s_setprio(1);
#pragma unroll
      for (int m = 0; m < MFRAG; ++m)
#pragma unroll
        for (int n = 0; n < NFRAG; ++n)
          acc[m][n] = mfma16(a[m], b[n], acc[m][n]);
      __builtin_amdgcn_s_setprio(0);
    }
    __syncthreads();
  }

#pragma unroll
  for (int m = 0; m < MFRAG; ++m)
#pragma unroll
    for (int n = 0; n < NFRAG; ++n) {
      const int jbase = j0 + wc * NFRAG * 16 + n * 16;
      const int ibase = i0 + wr * MFRAG * 16 + m * 16 + lr * 4;
      if constexpr (EPI == 0) {
        const int region = jbase >> 10;
        const int jc0 = jbase & 1023;
        const int h = jc0 >> 6, d0 = jc0 & 63;
        const int b = ibase >> 11, s0 = ibase & 2047;
        const size_t bh = (size_t)(b * NHEAD + h);
        if (region == 0) {
          float bb = biasQ[jc0 + lc];
#pragma unroll
          for (int r = 0; r < 4; ++r)
            Q[(bh * S_LEN + s0 + r) * HDIM + d0 + lc] =
                f2h((acc[m][n][r] + bb) * RCP_LN2);
        } else if (region == 1) {
          float bb = biasK[jc0 + lc];
#pragma unroll
          for (int r = 0; r < 4; ++r)
            Kd[(bh * S_LEN + s0 + r) * HDIM + d0 + lc] = f2h(acc[m][n][r] + bb);
        } else {
          float bb = biasV[jc0 + lc];
          ushort4 pv = make_ushort4(f2h(acc[m][n][0] + bb), f2h(acc[m][n][1] + bb),
                                    f2h(acc[m][n][2] + bb), f2h(acc[m][n][3] + bb));
          *(ushort4*)&Vt[(bh * HDIM + d0 + lc) * S_LEN + s0] = pv;
        }
      } else {
#pragma unroll
        for (int r = 0; r < 4; ++r)
          outF[(size_t)(ibase + r) * Ncols + jbase + lc] =
              acc[m][n][r] + biasQ[jbase + lc];
      }
    }
}

// ---------------- flash attention: barrier-free, K/V direct from L2 --------
// 768 blocks x 256 thr (4 waves), equalized split-K (R11 schedule).
// K and V fragments are read PER-LANE from global in MFMA layout (16B/lane,
// L1/L2-hot: per-XCD working set 2MB < 4MB L2; tiles 8KB fit L1). No K/V LDS,
// no staging, no vmcnt, NO BARRIERS - Plds is per-wave (DS in-order).
// LDS 18KB, ~5-8 blocks/CU for backfill. Lazy softmax (no steady shuffles).
__global__ __launch_bounds__(256, 4)
void attn_kernel(const ushort* __restrict__ Qp, const ushort* __restrict__ Kp,
                 const ushort* __restrict__ Vt, ushort* __restrict__ O,
                 float* __restrict__ Pacc, float* __restrict__ Pml)
{
  __shared__ ushort Plds[4][2][16][72];
  const int blk = blockIdx.x;
  const int c = blk & 255, s3 = blk >> 8;
  const int rank = (s3 == 0) ? c : ((s3 == 1) ? 511 - c : 512 + c);
  const int ty = rank >> 5, bh = rank & 31;
  const int qi = g_qi_tab[ty], hf = g_hf_tab[ty];
  const int nkt = 2 * qi + 2;
  const int kt0 = (hf == 1) ? (nkt >> 1) : 0;
  const int kt1 = (hf == 0) ? (nkt >> 1) : nkt;

  const int t = threadIdx.x, w = t >> 6, l = t & 63;
  const int g = l >> 4, q = l & 15;
  const size_t base = (size_t)bh * S_LEN * HDIM;
  const int q0w = qi * 128 + w * 32;

  // per-lane fragment pointers (advance per kt)
  // K frag (n,ks): K[base + (kt*64 + n*16 + q)*64 + ks*32 + g*8]
  const ushort* kp = Kp + base + (size_t)(kt0 * 64 + q) * HDIM + g * 8;
  // V frag (dt,ks): Vt[(bh*64 + dt*16 + q)*S_LEN + kt*64 + ks*32 + g*8]
  const ushort* vp = Vt + ((size_t)bh * HDIM + q) * S_LEN + (size_t)kt0 * 64 + g * 8;

  // Q as B-fragments for both subtiles; log2e-scaled
  f16x8 bQ[2][2];
#pragma unroll
  for (int u = 0; u < 2; ++u)
#pragma unroll
    for (int ks = 0; ks < 2; ++ks)
      bQ[u][ks] = *(const f16x8*)(Qp + base +
                  (size_t)(q0w + u * 16 + q) * HDIM + ks * 32 + g * 8);

  f32x4 oacc[2][4] = {};
  float m[2] = {-3e38f, -3e38f}, lsum[2] = {0.f, 0.f};  // lsum: per-lane partial

  for (int kt = kt0; kt < kt1; ++kt) {
    if (kt * 64 <= q0w + 31) {   // wave-level skip of fully-masked tiles
      // QK^T (swapped): K fragments straight from global (L1/L2)
      f32x4 s[2][4] = {};
      __builtin_amdgcn_s_setprio(1);
#pragma unroll
      for (int ks = 0; ks < 2; ++ks) {
#pragma unroll
        for (int n = 0; n < 4; ++n) {
          f16x8 kf = *(const f16x8*)(kp + n * 16 * HDIM + ks * 32);
          s[0][n] = mfma16(kf, bQ[0][ks], s[0][n]);
          s[1][n] = mfma16(kf, bQ[1][ks], s[1][n]);
        }
      }
      __builtin_amdgcn_s_setprio(0);
#pragma unroll
      for (int u = 0; u < 2; ++u) {
        if (kt * 64 + 63 > q0w + u * 16) {
          const int qg = q0w + u * 16 + q;
#pragma unroll
          for (int n = 0; n < 4; ++n)
#pragma unroll
            for (int r = 0; r < 4; ++r) {
              int kg = kt * 64 + n * 16 + g * 4 + r;
              if (kg > qg) s[u][n][r] = -1e30f;
            }
        }
      }
      // in-lane local max only (no shuffles steady-state)
      float pm[2];
#pragma unroll
      for (int u = 0; u < 2; ++u) {
        float p = -3e38f;
#pragma unroll
        for (int n = 0; n < 4; ++n)
          p = fmaxf(p, fmaxf(fmaxf(s[u][n][0], s[u][n][1]),
                             fmaxf(s[u][n][2], s[u][n][3])));
        pm[u] = p;
      }
      // trip test: exact ("column max > m+8" iff some lane's local max is)
#pragma unroll
      for (int u = 0; u < 2; ++u) {
        if (__any(pm[u] > m[u] + 8.0f)) {
          float pf = pm[u];
          pf = fmaxf(pf, __shfl_xor(pf, 16));
          pf = fmaxf(pf, __shfl_xor(pf, 32));
          float mnew = fmaxf(m[u], pf);
          float sc = fexp2(m[u] - mnew);
          m[u] = mnew;
          float scr[4];
#pragma unroll
          for (int r = 0; r < 4; ++r) scr[r] = __shfl(sc, g * 4 + r);
#pragma unroll
          for (int dt = 0; dt < 4; ++dt)
#pragma unroll
            for (int r = 0; r < 4; ++r) oacc[u][dt][r] *= scr[r];
          lsum[u] *= sc;
        }
      }
      // exp + per-lane partial sum (cross-g reduce deferred to epilogue)
#pragma unroll
      for (int u = 0; u < 2; ++u) {
        float rs = 0.f;
#pragma unroll
        for (int n = 0; n < 4; ++n)
#pragma unroll
          for (int r = 0; r < 4; ++r) {
            float pe = fexp2(s[u][n][r] - m[u]);
            s[u][n][r] = pe;
            rs += pe;
          }
        lsum[u] += rs;
      }
      // P^T -> per-wave LDS (both subtiles live: bv shared across u below)
#pragma unroll
      for (int u = 0; u < 2; ++u)
#pragma unroll
        for (int n = 0; n < 4; ++n) {
          uint2 pk = make_uint2(pkrtz(s[u][n][0], s[u][n][1]),
                                pkrtz(s[u][n][2], s[u][n][3]));
          *(uint2*)&Plds[w][u][q][n * 16 + g * 4] = pk;
        }
      // PV: V fragments straight from global; each bv feeds both subtiles
      __builtin_amdgcn_s_setprio(1);
#pragma unroll
      for (int ks = 0; ks < 2; ++ks) {
        f16x8 ap0 = *(const f16x8*)&Plds[w][0][q][ks * 32 + g * 8];
        f16x8 ap1 = *(const f16x8*)&Plds[w][1][q][ks * 32 + g * 8];
#pragma unroll
        for (int dt = 0; dt < 4; ++dt) {
          f16x8 bv = *(const f16x8*)(vp + (size_t)dt * 16 * S_LEN + ks * 32);
          oacc[0][dt] = mfma16(ap0, bv, oacc[0][dt]);
          oacc[1][dt] = mfma16(ap1, bv, oacc[1][dt]);
        }
      }
      __builtin_amdgcn_s_setprio(0);
    }
    kp += 64 * HDIM;
    vp += 64;
  }

  // epilogue: complete the deferred column-sum reduce (once per job)
#pragma unroll
  for (int u = 0; u < 2; ++u) {
    lsum[u] += __shfl_xor(lsum[u], 16);
    lsum[u] += __shfl_xor(lsum[u], 32);
  }

  if (hf == 2) {
    const int b = bh >> 4, h = bh & 15;
#pragma unroll
    for (int u = 0; u < 2; ++u) {
      float lsr[4];
#pragma unroll
      for (int r = 0; r < 4; ++r)
        lsr[r] = __builtin_amdgcn_rcpf(__shfl(lsum[u], g * 4 + r));
#pragma unroll
      for (int dt = 0; dt < 4; ++dt)
#pragma unroll
        for (int r = 0; r < 4; ++r) {
          int qg = q0w + u * 16 + g * 4 + r;
          O[((size_t)b * S_LEN + qg) * DM + h * HDIM + dt * 16 + q] =
              f2h(oacc[u][dt][r] * lsr[r]);
        }
    }
  } else {
    const int pidx = (bh * 8 + (qi - 8)) * 2 + hf;
    float* po = Pacc + (size_t)pidx * (128 * 64);
#pragma unroll
    for (int u = 0; u < 2; ++u) {
#pragma unroll
      for (int dt = 0; dt < 4; ++dt)
#pragma unroll
        for (int r = 0; r < 4; ++r)
          po[(w * 32 + u * 16 + g * 4 + r) * 64 + dt * 16 + q] = oacc[u][dt][r];
      if (g == 0) {
        Pml[(size_t)pidx * 256 + (w * 32 + u * 16 + q) * 2]     = m[u];
        Pml[(size_t)pidx * 256 + (w * 32 + u * 16 + q) * 2 + 1] = lsum[u];
      }
    }
  }
}

// ---------------- combine split-K partials (qi 8..15) ----------------
__global__ void combine_kernel(const float* __restrict__ Pacc,
                               const float* __restrict__ Pml,
                               ushort* __restrict__ O)
{
  int gid = blockIdx.x * 256 + threadIdx.x;
  int row = gid >> 6, col = gid & 63;
  int bh = row >> 10;
  int rr = row & 1023;
  int qi = 8 + (rr >> 7), qr = rr & 127;
  int p0 = (bh * 8 + (qi - 8)) * 2;
  float m1 = Pml[(size_t)p0 * 256 + qr * 2];
  float l1 = Pml[(size_t)p0 * 256 + qr * 2 + 1];
  float m2 = Pml[(size_t)(p0 + 1) * 256 + qr * 2];
  float l2 = Pml[(size_t)(p0 + 1) * 256 + qr * 2 + 1];
  float o1 = Pacc[(size_t)p0 * 8192 + qr * 64 + col];
  float o2 = Pacc[(size_t)(p0 + 1) * 8192 + qr * 64 + col];
  float mf = fmaxf(m1, m2);
  float e1 = fexp2(m1 - mf), e2 = fexp2(m2 - mf);
  float o = o1 * e1 + o2 * e2;
  float lden = l1 * e1 + l2 * e2;
  int b = bh >> 4, h = bh & 15;
  O[((size_t)b * S_LEN + qi * 128 + qr) * DM + h * HDIM + col] = f2h(o / lden);
}

extern "C" void kernel_launch(void* const* d_in, const int* in_sizes, int n_in,
                              void* d_out, int out_size, void* d_ws, size_t ws_size,
                              hipStream_t stream)
{
  const float* x  = (const float*)d_in[0];
  const float* Wq = (const float*)d_in[2];
  const float* bq = (const float*)d_in[3];
  const float* Wk = (const float*)d_in[4];
  const float* bk = (const float*)d_in[5];
  const float* Wv = (const float*)d_in[6];
  const float* bv = (const float*)d_in[7];
  const float* Wo = (const float*)d_in[8];
  const float* bo = (const float*)d_in[9];
  float* out = (float*)d_out;

  char* ws = (char*)d_ws;
  size_t off = 0;
  auto alloc = [&](size_t bytes) { char* p = ws + off; off += bytes; return p; };
  const size_t XN = (size_t)NROWS * DM;
  const size_t WN = (size_t)DM * DM;

  ushort* Xh  = (ushort*)alloc(XN * 2);
  ushort* Wh  = (ushort*)alloc(3 * WN * 2);
  ushort* Woh = (ushort*)alloc(WN * 2);
  ushort* Qb  = (ushort*)alloc(XN * 2);
  ushort* Kb  = (ushort*)alloc(XN * 2);
  ushort* Vt  = (ushort*)alloc(XN * 2);
  ushort* Ob  = (ushort*)alloc(XN * 2);
  float*  Pacc = (float*)alloc((size_t)512 * 128 * 64 * 4);
  float*  Pml  = (float*)alloc((size_t)512 * 256 * 4);
  (void)ws_size; (void)in_sizes; (void)n_in; (void)out_size;

  const int total4 = (int)(XN / 4 + 4 * (WN / 4));
  tohalf5<<<total4 / 256, 256, 0, stream>>>(x, Wq, Wk, Wv, Wo, Xh, Wh, Woh);

  gemm_half<0, 4, 4><<<dim3(24, 32), 256, 0, stream>>>(
      Xh, Wh, bq, bk, bv, nullptr, Qb, Kb, Vt, 3072);
  attn_kernel<<<768, 256, 0, stream>>>(Qb, Kb, Vt, Ob, Pacc, Pml);
  combine_kernel<<<8192, 256, 0, stream>>>(Pacc, Pml, Ob);
  gemm_half<1, 2, 2><<<dim3(16, 64), 256, 0, stream>>>(
      Ob, Woh, bo, nullptr, nullptr, out, nullptr, nullptr, nullptr, 1024);
}

// Round 14
// 100.359 us; speedup vs baseline: 1.3598x; 1.3598x over previous
//
#include <hip/hip_runtime.h>

#define S_LEN 2048
#define DM    1024
#define NHEAD 16
#define HDIM  64
#define NB    2
#define NROWS (NB * S_LEN)   // 4096
#define RCP_LN2 1.44269504f

using f32x4  = __attribute__((ext_vector_type(4))) float;
using f16x8  = __attribute__((ext_vector_type(8))) _Float16;

__device__ __forceinline__ ushort f2h(float f) {
  return __builtin_bit_cast(ushort, (_Float16)f);
}
__device__ __forceinline__ float h2f(ushort u) {
  return (float)__builtin_bit_cast(_Float16, u);
}
__device__ __forceinline__ unsigned pkrtz(float a, float b) {
  return __builtin_bit_cast(unsigned, __builtin_amdgcn_cvt_pkrtz(a, b));
}
__device__ __forceinline__ float fexp2(float x) {     // raw v_exp_f32
  return __builtin_amdgcn_exp2f(x);
}
__device__ __forceinline__ f32x4 mfma16(f16x8 a, f16x8 b, f32x4 c) {
  return __builtin_amdgcn_mfma_f32_16x16x32_f16(a, b, c, 0, 0, 0);
}
__device__ __forceinline__ void async16(const ushort* g, ushort* l) {
  __builtin_amdgcn_global_load_lds(
      (const __attribute__((address_space(1))) unsigned*)g,
      (__attribute__((address_space(3))) unsigned*)l, 16, 0, 0);
}

// job type tables (KVBLK=64 units): 24 types, sorted by length desc.
// hf: 0=front half, 1=back half, 2=whole
__device__ const int g_qi_tab[24] = {15,15,7,14,14,13,13,6,12,12,11,11,
                                     5,10,10,9,9,4,8,8,3,2,1,0};
__device__ const int g_hf_tab[24] = {0,1,2,0,1,0,1,2,0,1,0,1,
                                     2,0,1,0,1,2,0,1,2,2,2,2};

// ---------------- fused fp32 -> fp16 for x, Wq, Wk, Wv, Wo ----------------
__global__ void tohalf5(const float* __restrict__ x,  const float* __restrict__ wq,
                        const float* __restrict__ wk, const float* __restrict__ wv,
                        const float* __restrict__ wo,
                        ushort* __restrict__ Xh, ushort* __restrict__ Wh,
                        ushort* __restrict__ Woh) {
  constexpr int X4 = (NROWS * DM) / 4;
  constexpr int W4 = (DM * DM) / 4;
  const size_t WN = (size_t)DM * DM;
  int i = blockIdx.x * 256 + threadIdx.x;
  const float4* src; ushort4* dst; int k;
  if (i < X4)               { src = (const float4*)x;  dst = (ushort4*)Xh;        k = i; }
  else if (i < X4 + W4)     { src = (const float4*)wq; dst = (ushort4*)Wh;        k = i - X4; }
  else if (i < X4 + 2*W4)   { src = (const float4*)wk; dst = (ushort4*)(Wh+WN);   k = i - X4 - W4; }
  else if (i < X4 + 3*W4)   { src = (const float4*)wv; dst = (ushort4*)(Wh+2*WN); k = i - X4 - 2*W4; }
  else                      { src = (const float4*)wo; dst = (ushort4*)Woh;       k = i - X4 - 3*W4; }
  float4 v = src[k];
  dst[k] = make_ushort4(f2h(v.x), f2h(v.y), f2h(v.z), f2h(v.w));
}

// ---------------- fp16 NT GEMM: C = A[M,K] * (B[N,K])^T ----------------
template<int EPI, int MFRAG, int NFRAG>
__global__ __launch_bounds__(256, 2)
void gemm_half(const ushort* __restrict__ A, const ushort* __restrict__ B,
               const float* __restrict__ biasQ, const float* __restrict__ biasK,
               const float* __restrict__ biasV,
               float* __restrict__ outF,
               ushort* __restrict__ Q, ushort* __restrict__ Kd,
               ushort* __restrict__ Vt, int Ncols)
{
  constexpr int KD = 1024;
  constexpr int BM = MFRAG * 32, BN = NFRAG * 32;
  constexpr int NCH = (BM + BN) / 8;
  constexpr int CPW = NCH / 4;
  __shared__ ushort sL[(BM + BN) * 64];
  const int t = threadIdx.x;
  const int w = t >> 6, l = t & 63;
  const int lr = l >> 4, lc = l & 15;
  const int wr = w >> 1, wc = w & 1;
  const int nwg = gridDim.x * gridDim.y;
  const int lin = blockIdx.y * gridDim.x + blockIdx.x;
  const int per8 = nwg >> 3;
  const int swz = (lin & 7) * per8 + (lin >> 3);
  const int i0 = (swz / gridDim.x) * BM, j0 = (swz % gridDim.x) * BN;

  const int srow = l >> 3;
  const int se   = ((l & 7) ^ srow) << 3;

  const ushort* sp[CPW];
#pragma unroll
  for (int ii = 0; ii < CPW; ++ii) {
    const int c = w * CPW + ii;
    sp[ii] = (c < BM / 8)
        ? A + (size_t)(i0 + c * 8 + srow) * KD + se
        : B + (size_t)(j0 + (c - BM / 8) * 8 + srow) * KD + se;
  }

  f32x4 acc[MFRAG][NFRAG] = {};

  for (int k0 = 0; k0 < KD; k0 += 64) {
#pragma unroll
    for (int ii = 0; ii < CPW; ++ii) {
      async16(sp[ii], &sL[(w * CPW + ii) * 512]);
      sp[ii] += 64;
    }
    asm volatile("s_waitcnt vmcnt(0)" ::: "memory");
    __syncthreads();
#pragma unroll
    for (int kk = 0; kk < 2; ++kk) {
      const int cb = (kk * 64 + lr * 16) ^ ((lc & 7) << 4);
      f16x8 a[MFRAG], b[NFRAG];
#pragma unroll
      for (int m = 0; m < MFRAG; ++m)
        a[m] = *(const f16x8*)&sL[(wr * MFRAG * 16 + m * 16 + lc) * 64 + (cb >> 1)];
#pragma unroll
      for (int n = 0; n < NFRAG; ++n)
        b[n] = *(const f16x8*)&sL[BM * 64 + (wc * NFRAG * 16 + n * 16 + lc) * 64 + (cb >> 1)];
      __builtin_amdgcn_s_setprio(1);
#pragma unroll
      for (int m = 0; m < MFRAG; ++m)
#pragma unroll
        for (int n = 0; n < NFRAG; ++n)
          acc[m][n] = mfma16(a[m], b[n], acc[m][n]);
      __builtin_amdgcn_s_setprio(0);
    }
    __syncthreads();
  }

#pragma unroll
  for (int m = 0; m < MFRAG; ++m)
#pragma unroll
    for (int n = 0; n < NFRAG; ++n) {
      const int jbase = j0 + wc * NFRAG * 16 + n * 16;
      const int ibase = i0 + wr * MFRAG * 16 + m * 16 + lr * 4;
      if constexpr (EPI == 0) {
        const int region = jbase >> 10;
        const int jc0 = jbase & 1023;
        const int h = jc0 >> 6, d0 = jc0 & 63;
        const int b = ibase >> 11, s0 = ibase & 2047;
        const size_t bh = (size_t)(b * NHEAD + h);
        if (region == 0) {
          float bb = biasQ[jc0 + lc];
#pragma unroll
          for (int r = 0; r < 4; ++r)
            Q[(bh * S_LEN + s0 + r) * HDIM + d0 + lc] =
                f2h((acc[m][n][r] + bb) * RCP_LN2);
        } else if (region == 1) {
          float bb = biasK[jc0 + lc];
#pragma unroll
          for (int r = 0; r < 4; ++r)
            Kd[(bh * S_LEN + s0 + r) * HDIM + d0 + lc] = f2h(acc[m][n][r] + bb);
        } else {
          float bb = biasV[jc0 + lc];
          ushort4 pv = make_ushort4(f2h(acc[m][n][0] + bb), f2h(acc[m][n][1] + bb),
                                    f2h(acc[m][n][2] + bb), f2h(acc[m][n][3] + bb));
          *(ushort4*)&Vt[(bh * HDIM + d0 + lc) * S_LEN + s0] = pv;
        }
      } else {
#pragma unroll
        for (int r = 0; r < 4; ++r)
          outF[(size_t)(ibase + r) * Ncols + jbase + lc] =
              acc[m][n][r] + biasQ[jbase + lc];
      }
    }
}

// ---------------- flash attention: equalized split-K, lazy softmax ----------
// (R11 configuration - best measured.) 768 blocks x 256 thr (4 waves), 3/CU.
// dbuf LDS staging via global_load_lds; lazy softmax (no steady-state
// shuffles); fexp2; defer-max; setprio. Split jobs write fp16 partials.
__global__ __launch_bounds__(256, 3)
void attn_kernel(const ushort* __restrict__ Qp, const ushort* __restrict__ Kp,
                 const ushort* __restrict__ Vt, ushort* __restrict__ O,
                 ushort* __restrict__ Pacc, float* __restrict__ Pml)
{
  __shared__ ushort sKV[2][2 * 64 * 64];
  __shared__ ushort Plds[4][2][16][72];
  const int blk = blockIdx.x;
  const int c = blk & 255, s3 = blk >> 8;
  const int rank = (s3 == 0) ? c : ((s3 == 1) ? 511 - c : 512 + c);
  const int ty = rank >> 5, bh = rank & 31;
  const int qi = g_qi_tab[ty], hf = g_hf_tab[ty];
  const int nkt = 2 * qi + 2;
  const int kt0 = (hf == 1) ? (nkt >> 1) : 0;
  const int kt1 = (hf == 0) ? (nkt >> 1) : nkt;

  const int t = threadIdx.x, w = t >> 6, l = t & 63;
  const int g = l >> 4, q = l & 15;
  const size_t base = (size_t)bh * S_LEN * HDIM;
  const int q0w = qi * 128 + w * 32;

  const int srow = l >> 3;
  const int se   = ((l & 7) ^ srow) << 3;

  // hoisted staging pointers: waves 0-1 stage K, waves 2-3 stage V
  const int sel = w >> 1;
  const ushort* sp[4];
  const int sadv = (sel == 0) ? 64 * HDIM : 64;
#pragma unroll
  for (int ii = 0; ii < 4; ++ii) {
    const int sub = (w * 4 + ii) & 7;
    sp[ii] = (sel == 0)
        ? Kp + base + (size_t)(kt0 * 64 + sub * 8 + srow) * HDIM + se
        : Vt + ((size_t)bh * HDIM + sub * 8 + srow) * S_LEN + kt0 * 64 + se;
  }

  auto stage = [&](int buf) {
#pragma unroll
    for (int ii = 0; ii < 4; ++ii) {
      const int sub = (w * 4 + ii) & 7;
      async16(sp[ii], &sKV[buf][sel * 4096 + sub * 512]);
      sp[ii] += sadv;
    }
  };

  // Q as B-fragments for both subtiles; log2e-scaled
  f16x8 bQ[2][2];
#pragma unroll
  for (int u = 0; u < 2; ++u)
#pragma unroll
    for (int ks = 0; ks < 2; ++ks)
      bQ[u][ks] = *(const f16x8*)(Qp + base +
                  (size_t)(q0w + u * 16 + q) * HDIM + ks * 32 + g * 8);

  f32x4 oacc[2][4] = {};
  float m[2] = {-3e38f, -3e38f}, lsum[2] = {0.f, 0.f};   // lsum: per-lane partial

  stage(0);
  asm volatile("s_waitcnt vmcnt(0)" ::: "memory");
  __syncthreads();
  int cur = 0;

  for (int kt = kt0; kt < kt1; ++kt) {
    if (kt + 1 < kt1) stage(cur ^ 1);

    if (kt * 64 <= q0w + 31) {   // wave-level skip of fully-masked tiles
      f32x4 s[2][4] = {};
      __builtin_amdgcn_s_setprio(1);
#pragma unroll
      for (int ks = 0; ks < 2; ++ks) {
        const int cb = (((ks * 64 + g * 16) ^ ((q & 7) << 4)) >> 1);
#pragma unroll
        for (int n = 0; n < 4; ++n) {
          f16x8 kf = *(const f16x8*)&sKV[cur][(n * 16 + q) * 64 + cb];
          s[0][n] = mfma16(kf, bQ[0][ks], s[0][n]);
          s[1][n] = mfma16(kf, bQ[1][ks], s[1][n]);
        }
      }
      __builtin_amdgcn_s_setprio(0);
#pragma unroll
      for (int u = 0; u < 2; ++u) {
        if (kt * 64 + 63 > q0w + u * 16) {
          const int qg = q0w + u * 16 + q;
#pragma unroll
          for (int n = 0; n < 4; ++n)
#pragma unroll
            for (int r = 0; r < 4; ++r) {
              int kg = kt * 64 + n * 16 + g * 4 + r;
              if (kg > qg) s[u][n][r] = -1e30f;
            }
        }
      }
      // in-lane local max only (no shuffles in steady state)
      float pm[2];
#pragma unroll
      for (int u = 0; u < 2; ++u) {
        float p = -3e38f;
#pragma unroll
        for (int n = 0; n < 4; ++n)
          p = fmaxf(p, fmaxf(fmaxf(s[u][n][0], s[u][n][1]),
                             fmaxf(s[u][n][2], s[u][n][3])));
        pm[u] = p;
      }
      // trip test: exact ("column max > m+8" iff some lane's local max is)
#pragma unroll
      for (int u = 0; u < 2; ++u) {
        if (__any(pm[u] > m[u] + 8.0f)) {
          float pf = pm[u];                       // full column reduce (rare)
          pf = fmaxf(pf, __shfl_xor(pf, 16));
          pf = fmaxf(pf, __shfl_xor(pf, 32));
          float mnew = fmaxf(m[u], pf);
          float sc = fexp2(m[u] - mnew);
          m[u] = mnew;
          float scr[4];
#pragma unroll
          for (int r = 0; r < 4; ++r) scr[r] = __shfl(sc, g * 4 + r);
#pragma unroll
          for (int dt = 0; dt < 4; ++dt)
#pragma unroll
            for (int r = 0; r < 4; ++r) oacc[u][dt][r] *= scr[r];
          lsum[u] *= sc;
        }
      }
      // exp + per-lane partial sum (cross-g reduce deferred to epilogue)
#pragma unroll
      for (int u = 0; u < 2; ++u) {
        float rs = 0.f;
#pragma unroll
        for (int n = 0; n < 4; ++n)
#pragma unroll
          for (int r = 0; r < 4; ++r) {
            float pe = fexp2(s[u][n][r] - m[u]);
            s[u][n][r] = pe;
            rs += pe;
          }
        lsum[u] += rs;
      }
#pragma unroll
      for (int u = 0; u < 2; ++u)
#pragma unroll
        for (int n = 0; n < 4; ++n) {
          uint2 pk = make_uint2(pkrtz(s[u][n][0], s[u][n][1]),
                                pkrtz(s[u][n][2], s[u][n][3]));
          *(uint2*)&Plds[w][u][q][n * 16 + g * 4] = pk;
        }
      __builtin_amdgcn_s_setprio(1);
#pragma unroll
      for (int ks = 0; ks < 2; ++ks) {
        const int cb = (((ks * 64 + g * 16) ^ ((q & 7) << 4)) >> 1);
        f16x8 ap0 = *(const f16x8*)&Plds[w][0][q][ks * 32 + g * 8];
        f16x8 ap1 = *(const f16x8*)&Plds[w][1][q][ks * 32 + g * 8];
#pragma unroll
        for (int dt = 0; dt < 4; ++dt) {
          f16x8 bv = *(const f16x8*)&sKV[cur][4096 + (dt * 16 + q) * 64 + cb];
          oacc[0][dt] = mfma16(ap0, bv, oacc[0][dt]);
          oacc[1][dt] = mfma16(ap1, bv, oacc[1][dt]);
        }
      }
      __builtin_amdgcn_s_setprio(0);
    }
    asm volatile("s_waitcnt vmcnt(0)" ::: "memory");
    __syncthreads();
    cur ^= 1;
  }

  // epilogue: complete the deferred column-sum reduce (once per job)
#pragma unroll
  for (int u = 0; u < 2; ++u) {
    lsum[u] += __shfl_xor(lsum[u], 16);
    lsum[u] += __shfl_xor(lsum[u], 32);
  }

  if (hf == 2) {
    const int b = bh >> 4, h = bh & 15;
#pragma unroll
    for (int u = 0; u < 2; ++u) {
      float lsr[4];
#pragma unroll
      for (int r = 0; r < 4; ++r)
        lsr[r] = __builtin_amdgcn_rcpf(__shfl(lsum[u], g * 4 + r));
#pragma unroll
      for (int dt = 0; dt < 4; ++dt)
#pragma unroll
        for (int r = 0; r < 4; ++r) {
          int qg = q0w + u * 16 + g * 4 + r;
          O[((size_t)b * S_LEN + qg) * DM + h * HDIM + dt * 16 + q] =
              f2h(oacc[u][dt][r] * lsr[r]);
        }
    }
  } else {
    // fp16 partials (verified numerically safe in R12: absmax unchanged)
    const int pidx = (bh * 8 + (qi - 8)) * 2 + hf;
    ushort* po = Pacc + (size_t)pidx * (128 * 64);
#pragma unroll
    for (int u = 0; u < 2; ++u) {
#pragma unroll
      for (int dt = 0; dt < 4; ++dt)
#pragma unroll
        for (int r = 0; r < 4; ++r)
          po[(w * 32 + u * 16 + g * 4 + r) * 64 + dt * 16 + q] = f2h(oacc[u][dt][r]);
      if (g == 0) {
        Pml[(size_t)pidx * 256 + (w * 32 + u * 16 + q) * 2]     = m[u];
        Pml[(size_t)pidx * 256 + (w * 32 + u * 16 + q) * 2 + 1] = lsum[u];
      }
    }
  }
}

// ---------------- combine split-K partials (qi 8..15) ----------------
__global__ void combine_kernel(const ushort* __restrict__ Pacc,
                               const float* __restrict__ Pml,
                               ushort* __restrict__ O)
{
  int gid = blockIdx.x * 256 + threadIdx.x;
  int row = gid >> 6, col = gid & 63;
  int bh = row >> 10;
  int rr = row & 1023;
  int qi = 8 + (rr >> 7), qr = rr & 127;
  int p0 = (bh * 8 + (qi - 8)) * 2;
  float m1 = Pml[(size_t)p0 * 256 + qr * 2];
  float l1 = Pml[(size_t)p0 * 256 + qr * 2 + 1];
  float m2 = Pml[(size_t)(p0 + 1) * 256 + qr * 2];
  float l2 = Pml[(size_t)(p0 + 1) * 256 + qr * 2 + 1];
  float o1 = h2f(Pacc[(size_t)p0 * 8192 + qr * 64 + col]);
  float o2 = h2f(Pacc[(size_t)(p0 + 1) * 8192 + qr * 64 + col]);
  float mf = fmaxf(m1, m2);
  float e1 = fexp2(m1 - mf), e2 = fexp2(m2 - mf);
  float o = o1 * e1 + o2 * e2;
  float lden = l1 * e1 + l2 * e2;
  int b = bh >> 4, h = bh & 15;
  O[((size_t)b * S_LEN + qi * 128 + qr) * DM + h * HDIM + col] = f2h(o / lden);
}

extern "C" void kernel_launch(void* const* d_in, const int* in_sizes, int n_in,
                              void* d_out, int out_size, void* d_ws, size_t ws_size,
                              hipStream_t stream)
{
  const float* x  = (const float*)d_in[0];
  const float* Wq = (const float*)d_in[2];
  const float* bq = (const float*)d_in[3];
  const float* Wk = (const float*)d_in[4];
  const float* bk = (const float*)d_in[5];
  const float* Wv = (const float*)d_in[6];
  const float* bv = (const float*)d_in[7];
  const float* Wo = (const float*)d_in[8];
  const float* bo = (const float*)d_in[9];
  float* out = (float*)d_out;

  char* ws = (char*)d_ws;
  size_t off = 0;
  auto alloc = [&](size_t bytes) { char* p = ws + off; off += bytes; return p; };
  const size_t XN = (size_t)NROWS * DM;
  const size_t WN = (size_t)DM * DM;

  ushort* Xh  = (ushort*)alloc(XN * 2);
  ushort* Wh  = (ushort*)alloc(3 * WN * 2);
  ushort* Woh = (ushort*)alloc(WN * 2);
  ushort* Qb  = (ushort*)alloc(XN * 2);
  ushort* Kb  = (ushort*)alloc(XN * 2);
  ushort* Vt  = (ushort*)alloc(XN * 2);
  ushort* Ob  = (ushort*)alloc(XN * 2);
  ushort* Pacc = (ushort*)alloc((size_t)512 * 128 * 64 * 2);   // 8.4 MB fp16
  float*  Pml  = (float*)alloc((size_t)512 * 256 * 4);
  (void)ws_size; (void)in_sizes; (void)n_in; (void)out_size;

  const int total4 = (int)(XN / 4 + 4 * (WN / 4));
  tohalf5<<<total4 / 256, 256, 0, stream>>>(x, Wq, Wk, Wv, Wo, Xh, Wh, Woh);

  gemm_half<0, 4, 4><<<dim3(24, 32), 256, 0, stream>>>(
      Xh, Wh, bq, bk, bv, nullptr, Qb, Kb, Vt, 3072);
  attn_kernel<<<768, 256, 0, stream>>>(Qb, Kb, Vt, Ob, Pacc, Pml);
  combine_kernel<<<8192, 256, 0, stream>>>(Pacc, Pml, Ob);
  gemm_half<1, 2, 2><<<dim3(16, 64), 256, 0, stream>>>(
      Ob, Woh, bo, nullptr, nullptr, out, nullptr, nullptr, nullptr, 1024);
}

// Round 15
// 99.191 us; speedup vs baseline: 1.3758x; 1.0118x over previous
//
#include <hip/hip_runtime.h>

#define S_LEN 2048
#define DM    1024
#define NHEAD 16
#define HDIM  64
#define NB    2
#define NROWS (NB * S_LEN)   // 4096
#define RCP_LN2 1.44269504f

using f32x4  = __attribute__((ext_vector_type(4))) float;
using f16x8  = __attribute__((ext_vector_type(8))) _Float16;

__device__ __forceinline__ ushort f2h(float f) {
  return __builtin_bit_cast(ushort, (_Float16)f);
}
__device__ __forceinline__ float h2f(ushort u) {
  return (float)__builtin_bit_cast(_Float16, u);
}
__device__ __forceinline__ unsigned pkrtz(float a, float b) {
  return __builtin_bit_cast(unsigned, __builtin_amdgcn_cvt_pkrtz(a, b));
}
__device__ __forceinline__ float fexp2(float x) {     // raw v_exp_f32
  return __builtin_amdgcn_exp2f(x);
}
__device__ __forceinline__ f32x4 mfma16(f16x8 a, f16x8 b, f32x4 c) {
  return __builtin_amdgcn_mfma_f32_16x16x32_f16(a, b, c, 0, 0, 0);
}
__device__ __forceinline__ void async16(const ushort* g, ushort* l) {
  __builtin_amdgcn_global_load_lds(
      (const __attribute__((address_space(1))) unsigned*)g,
      (__attribute__((address_space(3))) unsigned*)l, 16, 0, 0);
}

// job type tables (KVBLK=64 units): 24 types, sorted by length desc.
// hf: 0=front half, 1=back half, 2=whole
__device__ const int g_qi_tab[24] = {15,15,7,14,14,13,13,6,12,12,11,11,
                                     5,10,10,9,9,4,8,8,3,2,1,0};
__device__ const int g_hf_tab[24] = {0,1,2,0,1,0,1,2,0,1,0,1,
                                     2,0,1,0,1,2,0,1,2,2,2,2};

// ---------------- fused fp32 -> fp16 for x, Wq, Wk, Wv, Wo ----------------
__global__ void tohalf5(const float* __restrict__ x,  const float* __restrict__ wq,
                        const float* __restrict__ wk, const float* __restrict__ wv,
                        const float* __restrict__ wo,
                        ushort* __restrict__ Xh, ushort* __restrict__ Wh,
                        ushort* __restrict__ Woh) {
  constexpr int X4 = (NROWS * DM) / 4;
  constexpr int W4 = (DM * DM) / 4;
  const size_t WN = (size_t)DM * DM;
  int i = blockIdx.x * 256 + threadIdx.x;
  const float4* src; ushort4* dst; int k;
  if (i < X4)               { src = (const float4*)x;  dst = (ushort4*)Xh;        k = i; }
  else if (i < X4 + W4)     { src = (const float4*)wq; dst = (ushort4*)Wh;        k = i - X4; }
  else if (i < X4 + 2*W4)   { src = (const float4*)wk; dst = (ushort4*)(Wh+WN);   k = i - X4 - W4; }
  else if (i < X4 + 3*W4)   { src = (const float4*)wv; dst = (ushort4*)(Wh+2*WN); k = i - X4 - 2*W4; }
  else                      { src = (const float4*)wo; dst = (ushort4*)Woh;       k = i - X4 - 3*W4; }
  float4 v = src[k];
  dst[k] = make_ushort4(f2h(v.x), f2h(v.y), f2h(v.z), f2h(v.w));
}

// ---------------- fp16 NT GEMM: C = A[M,K] * (B[N,K])^T ----------------
template<int EPI, int MFRAG, int NFRAG>
__global__ __launch_bounds__(256, 2)
void gemm_half(const ushort* __restrict__ A, const ushort* __restrict__ B,
               const float* __restrict__ biasQ, const float* __restrict__ biasK,
               const float* __restrict__ biasV,
               float* __restrict__ outF,
               ushort* __restrict__ Q, ushort* __restrict__ Kd,
               ushort* __restrict__ Vt, int Ncols)
{
  constexpr int KD = 1024;
  constexpr int BM = MFRAG * 32, BN = NFRAG * 32;
  constexpr int NCH = (BM + BN) / 8;
  constexpr int CPW = NCH / 4;
  __shared__ ushort sL[(BM + BN) * 64];
  const int t = threadIdx.x;
  const int w = t >> 6, l = t & 63;
  const int lr = l >> 4, lc = l & 15;
  const int wr = w >> 1, wc = w & 1;
  const int nwg = gridDim.x * gridDim.y;
  const int lin = blockIdx.y * gridDim.x + blockIdx.x;
  const int per8 = nwg >> 3;
  const int swz = (lin & 7) * per8 + (lin >> 3);
  const int i0 = (swz / gridDim.x) * BM, j0 = (swz % gridDim.x) * BN;

  const int srow = l >> 3;
  const int se   = ((l & 7) ^ srow) << 3;

  const ushort* sp[CPW];
#pragma unroll
  for (int ii = 0; ii < CPW; ++ii) {
    const int c = w * CPW + ii;
    sp[ii] = (c < BM / 8)
        ? A + (size_t)(i0 + c * 8 + srow) * KD + se
        : B + (size_t)(j0 + (c - BM / 8) * 8 + srow) * KD + se;
  }

  f32x4 acc[MFRAG][NFRAG] = {};

  for (int k0 = 0; k0 < KD; k0 += 64) {
#pragma unroll
    for (int ii = 0; ii < CPW; ++ii) {
      async16(sp[ii], &sL[(w * CPW + ii) * 512]);
      sp[ii] += 64;
    }
    asm volatile("s_waitcnt vmcnt(0)" ::: "memory");
    __syncthreads();
#pragma unroll
    for (int kk = 0; kk < 2; ++kk) {
      const int cb = (kk * 64 + lr * 16) ^ ((lc & 7) << 4);
      f16x8 a[MFRAG], b[NFRAG];
#pragma unroll
      for (int m = 0; m < MFRAG; ++m)
        a[m] = *(const f16x8*)&sL[(wr * MFRAG * 16 + m * 16 + lc) * 64 + (cb >> 1)];
#pragma unroll
      for (int n = 0; n < NFRAG; ++n)
        b[n] = *(const f16x8*)&sL[BM * 64 + (wc * NFRAG * 16 + n * 16 + lc) * 64 + (cb >> 1)];
      __builtin_amdgcn_s_setprio(1);
#pragma unroll
      for (int m = 0; m < MFRAG; ++m)
#pragma unroll
        for (int n = 0; n < NFRAG; ++n)
          acc[m][n] = mfma16(a[m], b[n], acc[m][n]);
      __builtin_amdgcn_s_setprio(0);
    }
    __syncthreads();
  }

#pragma unroll
  for (int m = 0; m < MFRAG; ++m)
#pragma unroll
    for (int n = 0; n < NFRAG; ++n) {
      const int jbase = j0 + wc * NFRAG * 16 + n * 16;
      const int ibase = i0 + wr * MFRAG * 16 + m * 16 + lr * 4;
      if constexpr (EPI == 0) {
        const int region = jbase >> 10;
        const int jc0 = jbase & 1023;
        const int h = jc0 >> 6, d0 = jc0 & 63;
        const int b = ibase >> 11, s0 = ibase & 2047;
        const size_t bh = (size_t)(b * NHEAD + h);
        if (region == 0) {
          float bb = biasQ[jc0 + lc];
#pragma unroll
          for (int r = 0; r < 4; ++r)
            Q[(bh * S_LEN + s0 + r) * HDIM + d0 + lc] =
                f2h((acc[m][n][r] + bb) * RCP_LN2);
        } else if (region == 1) {
          float bb = biasK[jc0 + lc];
#pragma unroll
          for (int r = 0; r < 4; ++r)
            Kd[(bh * S_LEN + s0 + r) * HDIM + d0 + lc] = f2h(acc[m][n][r] + bb);
        } else {
          float bb = biasV[jc0 + lc];
          ushort4 pv = make_ushort4(f2h(acc[m][n][0] + bb), f2h(acc[m][n][1] + bb),
                                    f2h(acc[m][n][2] + bb), f2h(acc[m][n][3] + bb));
          *(ushort4*)&Vt[(bh * HDIM + d0 + lc) * S_LEN + s0] = pv;
        }
      } else {
#pragma unroll
        for (int r = 0; r < 4; ++r)
          outF[(size_t)(ibase + r) * Ncols + jbase + lc] =
              acc[m][n][r] + biasQ[jbase + lc];
      }
    }
}

// ---------------- flash attention: equalized split-K, lazy softmax ----------
// (R11/R14 configuration - best measured.) 768 blocks x 256 thr (4 waves),
// 3/CU. dbuf LDS staging via global_load_lds; lazy softmax (no steady-state
// shuffles); fexp2; defer-max; setprio. Split jobs write fp16 partials.
__global__ __launch_bounds__(256, 3)
void attn_kernel(const ushort* __restrict__ Qp, const ushort* __restrict__ Kp,
                 const ushort* __restrict__ Vt, ushort* __restrict__ O,
                 ushort* __restrict__ Pacc, float* __restrict__ Pml)
{
  __shared__ ushort sKV[2][2 * 64 * 64];
  __shared__ ushort Plds[4][2][16][72];
  const int blk = blockIdx.x;
  const int c = blk & 255, s3 = blk >> 8;
  const int rank = (s3 == 0) ? c : ((s3 == 1) ? 511 - c : 512 + c);
  const int ty = rank >> 5, bh = rank & 31;
  const int qi = g_qi_tab[ty], hf = g_hf_tab[ty];
  const int nkt = 2 * qi + 2;
  const int kt0 = (hf == 1) ? (nkt >> 1) : 0;
  const int kt1 = (hf == 0) ? (nkt >> 1) : nkt;

  const int t = threadIdx.x, w = t >> 6, l = t & 63;
  const int g = l >> 4, q = l & 15;
  const size_t base = (size_t)bh * S_LEN * HDIM;
  const int q0w = qi * 128 + w * 32;

  const int srow = l >> 3;
  const int se   = ((l & 7) ^ srow) << 3;

  // hoisted staging pointers: waves 0-1 stage K, waves 2-3 stage V
  const int sel = w >> 1;
  const ushort* sp[4];
  const int sadv = (sel == 0) ? 64 * HDIM : 64;
#pragma unroll
  for (int ii = 0; ii < 4; ++ii) {
    const int sub = (w * 4 + ii) & 7;
    sp[ii] = (sel == 0)
        ? Kp + base + (size_t)(kt0 * 64 + sub * 8 + srow) * HDIM + se
        : Vt + ((size_t)bh * HDIM + sub * 8 + srow) * S_LEN + kt0 * 64 + se;
  }

  auto stage = [&](int buf) {
#pragma unroll
    for (int ii = 0; ii < 4; ++ii) {
      const int sub = (w * 4 + ii) & 7;
      async16(sp[ii], &sKV[buf][sel * 4096 + sub * 512]);
      sp[ii] += sadv;
    }
  };

  // Q as B-fragments for both subtiles; log2e-scaled
  f16x8 bQ[2][2];
#pragma unroll
  for (int u = 0; u < 2; ++u)
#pragma unroll
    for (int ks = 0; ks < 2; ++ks)
      bQ[u][ks] = *(const f16x8*)(Qp + base +
                  (size_t)(q0w + u * 16 + q) * HDIM + ks * 32 + g * 8);

  f32x4 oacc[2][4] = {};
  float m[2] = {-3e38f, -3e38f}, lsum[2] = {0.f, 0.f};   // lsum: per-lane partial

  stage(0);
  asm volatile("s_waitcnt vmcnt(0)" ::: "memory");
  __syncthreads();
  int cur = 0;

  for (int kt = kt0; kt < kt1; ++kt) {
    if (kt + 1 < kt1) stage(cur ^ 1);

    if (kt * 64 <= q0w + 31) {   // wave-level skip of fully-masked tiles
      f32x4 s[2][4] = {};
      __builtin_amdgcn_s_setprio(1);
#pragma unroll
      for (int ks = 0; ks < 2; ++ks) {
        const int cb = (((ks * 64 + g * 16) ^ ((q & 7) << 4)) >> 1);
#pragma unroll
        for (int n = 0; n < 4; ++n) {
          f16x8 kf = *(const f16x8*)&sKV[cur][(n * 16 + q) * 64 + cb];
          s[0][n] = mfma16(kf, bQ[0][ks], s[0][n]);
          s[1][n] = mfma16(kf, bQ[1][ks], s[1][n]);
        }
      }
      __builtin_amdgcn_s_setprio(0);
#pragma unroll
      for (int u = 0; u < 2; ++u) {
        if (kt * 64 + 63 > q0w + u * 16) {
          const int qg = q0w + u * 16 + q;
#pragma unroll
          for (int n = 0; n < 4; ++n)
#pragma unroll
            for (int r = 0; r < 4; ++r) {
              int kg = kt * 64 + n * 16 + g * 4 + r;
              if (kg > qg) s[u][n][r] = -1e30f;
            }
        }
      }
      // in-lane local max only (no shuffles in steady state)
      float pm[2];
#pragma unroll
      for (int u = 0; u < 2; ++u) {
        float p = -3e38f;
#pragma unroll
        for (int n = 0; n < 4; ++n)
          p = fmaxf(p, fmaxf(fmaxf(s[u][n][0], s[u][n][1]),
                             fmaxf(s[u][n][2], s[u][n][3])));
        pm[u] = p;
      }
      // trip test: exact ("column max > m+8" iff some lane's local max is)
#pragma unroll
      for (int u = 0; u < 2; ++u) {
        if (__any(pm[u] > m[u] + 8.0f)) {
          float pf = pm[u];                       // full column reduce (rare)
          pf = fmaxf(pf, __shfl_xor(pf, 16));
          pf = fmaxf(pf, __shfl_xor(pf, 32));
          float mnew = fmaxf(m[u], pf);
          float sc = fexp2(m[u] - mnew);
          m[u] = mnew;
          float scr[4];
#pragma unroll
          for (int r = 0; r < 4; ++r) scr[r] = __shfl(sc, g * 4 + r);
#pragma unroll
          for (int dt = 0; dt < 4; ++dt)
#pragma unroll
            for (int r = 0; r < 4; ++r) oacc[u][dt][r] *= scr[r];
          lsum[u] *= sc;
        }
      }
      // exp + per-lane partial sum (cross-g reduce deferred to epilogue)
#pragma unroll
      for (int u = 0; u < 2; ++u) {
        float rs = 0.f;
#pragma unroll
        for (int n = 0; n < 4; ++n)
#pragma unroll
          for (int r = 0; r < 4; ++r) {
            float pe = fexp2(s[u][n][r] - m[u]);
            s[u][n][r] = pe;
            rs += pe;
          }
        lsum[u] += rs;
      }
#pragma unroll
      for (int u = 0; u < 2; ++u)
#pragma unroll
        for (int n = 0; n < 4; ++n) {
          uint2 pk = make_uint2(pkrtz(s[u][n][0], s[u][n][1]),
                                pkrtz(s[u][n][2], s[u][n][3]));
          *(uint2*)&Plds[w][u][q][n * 16 + g * 4] = pk;
        }
      __builtin_amdgcn_s_setprio(1);
#pragma unroll
      for (int ks = 0; ks < 2; ++ks) {
        const int cb = (((ks * 64 + g * 16) ^ ((q & 7) << 4)) >> 1);
        f16x8 ap0 = *(const f16x8*)&Plds[w][0][q][ks * 32 + g * 8];
        f16x8 ap1 = *(const f16x8*)&Plds[w][1][q][ks * 32 + g * 8];
#pragma unroll
        for (int dt = 0; dt < 4; ++dt) {
          f16x8 bv = *(const f16x8*)&sKV[cur][4096 + (dt * 16 + q) * 64 + cb];
          oacc[0][dt] = mfma16(ap0, bv, oacc[0][dt]);
          oacc[1][dt] = mfma16(ap1, bv, oacc[1][dt]);
        }
      }
      __builtin_amdgcn_s_setprio(0);
    }
    asm volatile("s_waitcnt vmcnt(0)" ::: "memory");
    __syncthreads();
    cur ^= 1;
  }

  // epilogue: complete the deferred column-sum reduce (once per job)
#pragma unroll
  for (int u = 0; u < 2; ++u) {
    lsum[u] += __shfl_xor(lsum[u], 16);
    lsum[u] += __shfl_xor(lsum[u], 32);
  }

  if (hf == 2) {
    const int b = bh >> 4, h = bh & 15;
#pragma unroll
    for (int u = 0; u < 2; ++u) {
      float lsr[4];
#pragma unroll
      for (int r = 0; r < 4; ++r)
        lsr[r] = __builtin_amdgcn_rcpf(__shfl(lsum[u], g * 4 + r));
#pragma unroll
      for (int dt = 0; dt < 4; ++dt)
#pragma unroll
        for (int r = 0; r < 4; ++r) {
          int qg = q0w + u * 16 + g * 4 + r;
          O[((size_t)b * S_LEN + qg) * DM + h * HDIM + dt * 16 + q] =
              f2h(oacc[u][dt][r] * lsr[r]);
        }
    }
  } else {
    // fp16 partials (verified numerically safe in R12: absmax unchanged)
    const int pidx = (bh * 8 + (qi - 8)) * 2 + hf;
    ushort* po = Pacc + (size_t)pidx * (128 * 64);
#pragma unroll
    for (int u = 0; u < 2; ++u) {
#pragma unroll
      for (int dt = 0; dt < 4; ++dt)
#pragma unroll
        for (int r = 0; r < 4; ++r)
          po[(w * 32 + u * 16 + g * 4 + r) * 64 + dt * 16 + q] = f2h(oacc[u][dt][r]);
      if (g == 0) {
        Pml[(size_t)pidx * 256 + (w * 32 + u * 16 + q) * 2]     = m[u];
        Pml[(size_t)pidx * 256 + (w * 32 + u * 16 + q) * 2 + 1] = lsum[u];
      }
    }
  }
}

// ---------------- combine split-K partials (qi 8..15), 4 cols/thread -------
__global__ void combine_kernel(const ushort* __restrict__ Pacc,
                               const float* __restrict__ Pml,
                               ushort* __restrict__ O)
{
  int gid = blockIdx.x * 256 + threadIdx.x;   // 32 bh x 1024 rows x 16 quads
  int cq  = gid & 15;
  int rr  = (gid >> 4) & 1023;
  int bh  = gid >> 14;
  int qi = 8 + (rr >> 7), qr = rr & 127;
  int p0 = (bh * 8 + (qi - 8)) * 2;
  float m1 = Pml[(size_t)p0 * 256 + qr * 2];
  float l1 = Pml[(size_t)p0 * 256 + qr * 2 + 1];
  float m2 = Pml[(size_t)(p0 + 1) * 256 + qr * 2];
  float l2 = Pml[(size_t)(p0 + 1) * 256 + qr * 2 + 1];
  ushort4 o1 = *(const ushort4*)&Pacc[(size_t)p0 * 8192 + qr * 64 + cq * 4];
  ushort4 o2 = *(const ushort4*)&Pacc[(size_t)(p0 + 1) * 8192 + qr * 64 + cq * 4];
  float mf = fmaxf(m1, m2);
  float e1 = fexp2(m1 - mf), e2 = fexp2(m2 - mf);
  float rl = __builtin_amdgcn_rcpf(l1 * e1 + l2 * e2);
  ushort4 o;
  o.x = f2h((h2f(o1.x) * e1 + h2f(o2.x) * e2) * rl);
  o.y = f2h((h2f(o1.y) * e1 + h2f(o2.y) * e2) * rl);
  o.z = f2h((h2f(o1.z) * e1 + h2f(o2.z) * e2) * rl);
  o.w = f2h((h2f(o1.w) * e1 + h2f(o2.w) * e2) * rl);
  int b = bh >> 4, h = bh & 15;
  *(ushort4*)&O[((size_t)b * S_LEN + qi * 128 + qr) * DM + h * HDIM + cq * 4] = o;
}

extern "C" void kernel_launch(void* const* d_in, const int* in_sizes, int n_in,
                              void* d_out, int out_size, void* d_ws, size_t ws_size,
                              hipStream_t stream)
{
  const float* x  = (const float*)d_in[0];
  const float* Wq = (const float*)d_in[2];
  const float* bq = (const float*)d_in[3];
  const float* Wk = (const float*)d_in[4];
  const float* bk = (const float*)d_in[5];
  const float* Wv = (const float*)d_in[6];
  const float* bv = (const float*)d_in[7];
  const float* Wo = (const float*)d_in[8];
  const float* bo = (const float*)d_in[9];
  float* out = (float*)d_out;

  char* ws = (char*)d_ws;
  size_t off = 0;
  auto alloc = [&](size_t bytes) { char* p = ws + off; off += bytes; return p; };
  const size_t XN = (size_t)NROWS * DM;
  const size_t WN = (size_t)DM * DM;

  ushort* Xh  = (ushort*)alloc(XN * 2);
  ushort* Wh  = (ushort*)alloc(3 * WN * 2);
  ushort* Woh = (ushort*)alloc(WN * 2);
  ushort* Qb  = (ushort*)alloc(XN * 2);
  ushort* Kb  = (ushort*)alloc(XN * 2);
  ushort* Vt  = (ushort*)alloc(XN * 2);
  ushort* Ob  = (ushort*)alloc(XN * 2);
  ushort* Pacc = (ushort*)alloc((size_t)512 * 128 * 64 * 2);   // 8.4 MB fp16
  float*  Pml  = (float*)alloc((size_t)512 * 256 * 4);
  (void)ws_size; (void)in_sizes; (void)n_in; (void)out_size;

  const int total4 = (int)(XN / 4 + 4 * (WN / 4));
  tohalf5<<<total4 / 256, 256, 0, stream>>>(x, Wq, Wk, Wv, Wo, Xh, Wh, Woh);

  gemm_half<0, 4, 4><<<dim3(24, 32), 256, 0, stream>>>(
      Xh, Wh, bq, bk, bv, nullptr, Qb, Kb, Vt, 3072);
  attn_kernel<<<768, 256, 0, stream>>>(Qb, Kb, Vt, Ob, Pacc, Pml);
  combine_kernel<<<2048, 256, 0, stream>>>(Pacc, Pml, Ob);
  gemm_half<1, 2, 4><<<dim3(8, 64), 256, 0, stream>>>(
      Ob, Woh, bo, nullptr, nullptr, out, nullptr, nullptr, nullptr, 1024);
}